// Round 4
// baseline (262.040 us; speedup 1.0000x reference)
//
#include <hip/hip_runtime.h>
#include <math.h>

#define BATCH 32
#define CH    256
#define HH    56
#define WW    56
#define HW    3136
#define KS    7
#define KK    49
#define NIMG  8192           // BATCH*CH
// conv per-wave tile: 14 output rows -> 20 padded input rows x 62 padded cols
#define TPITCH 62
#define TROWS  20
#define TSIZE  (TPITCH * TROWS)   // 1240 floats per wave

// ---- Kernel 1: 8x8 block-mean pool -> p[img][49] + per-image (sum,sumsq) ----
// 4 waves/block, 1 image/wave, no barriers. Wave reads its image as 784 float4
// with lane-linear indexing (64 consecutive lanes = 1KB contiguous per instr),
// accumulates 8x8 cells via LDS float atomics, then wave-reduces stats.
__global__ __launch_bounds__(256) void pool_kernel(const float* __restrict__ x,
                                                   float* __restrict__ p,
                                                   float2* __restrict__ ss) {
    __shared__ float cells[4][KK];
    const int t = threadIdx.x;
    const int wid = t >> 6, lane = t & 63;
    const int img = blockIdx.x * 4 + wid;
    float* cw = cells[wid];
    if (lane < KK) cw[lane] = 0.f;
    asm volatile("s_waitcnt lgkmcnt(0)" ::: "memory");
    __builtin_amdgcn_wave_barrier();
    const float4* xp = (const float4*)(x + (size_t)img * HW);   // 784 float4
    #pragma unroll
    for (int k = 0; k < 13; ++k) {
        const int j = k * 64 + lane;
        if (j < 784) {
            const float4 v = xp[j];
            const int r = j / 14, q = j - r * 14;
            atomicAdd(&cw[(r >> 3) * KS + (q >> 1)], (v.x + v.y) + (v.z + v.w));
        }
    }
    asm volatile("s_waitcnt lgkmcnt(0)" ::: "memory");
    __builtin_amdgcn_wave_barrier();
    float v = 0.f;
    if (lane < KK) {
        v = cw[lane] * (1.0f / 64.0f);
        p[(size_t)img * KK + lane] = v;
    }
    float v2 = v * v;
    #pragma unroll
    for (int o = 32; o >= 1; o >>= 1) {
        v  += __shfl_down(v,  o, 64);
        v2 += __shfl_down(v2, o, 64);
    }
    if (lane == 0) ss[img] = make_float2(v, v2);
}

// --- Kernel 2: BN finalize+apply + Linear(49->7) + LN(C,7) + sigmoid + Linear(7->49) ---
__global__ __launch_bounds__(256) void mid_kernel(const float* __restrict__ p,
                                                  const float2* __restrict__ ss,
                                                  const float* __restrict__ bng,
                                                  const float* __restrict__ bnb,
                                                  const float* __restrict__ w0,
                                                  const float* __restrict__ lng,
                                                  const float* __restrict__ lnb,
                                                  const float* __restrict__ w1,
                                                  float* __restrict__ ker) {
    const int b = blockIdx.x, c = threadIdx.x;
    __shared__ float s_w0[KS * KK], s_w1[KK * KS];
    __shared__ float r1[4], r2[4];
    for (int i = c; i < KS * KK; i += 256) { s_w0[i] = w0[i]; s_w1[i] = w1[i]; }
    float S = 0.f, S2 = 0.f;
    #pragma unroll 4
    for (int bb = 0; bb < BATCH; ++bb) {
        const float2 t2 = ss[(size_t)bb * CH + c];
        S += t2.x; S2 += t2.y;
    }
    {
        const float inv  = 1.0f / (float)(BATCH * KK);
        const float mu   = S * inv;
        const float var  = S2 * inv - mu * mu;      // biased, matches ref
        const float rstd = rsqrtf(var + 1e-5f);
        S  = bng[c] * rstd;                         // scale
        S2 = bnb[c] - mu * S;                       // shift
    }
    __syncthreads();
    float pn[KK];
    const float* pp = p + ((size_t)b * CH + c) * KK;
    #pragma unroll
    for (int i = 0; i < KK; ++i) pn[i] = pp[i] * S + S2;
    float v[KS];
    float ls = 0.f, ls2 = 0.f;
    #pragma unroll
    for (int j = 0; j < KS; ++j) {
        float a = 0.f;
        #pragma unroll
        for (int i = 0; i < KK; ++i) a += pn[i] * s_w0[j * KK + i];   // v = pn @ w0^T
        v[j] = a; ls += a; ls2 += a * a;
    }
    #pragma unroll
    for (int o = 32; o >= 1; o >>= 1) {
        ls  += __shfl_down(ls, o, 64);
        ls2 += __shfl_down(ls2, o, 64);
    }
    const int w = threadIdx.x >> 6;
    if ((threadIdx.x & 63) == 0) { r1[w] = ls; r2[w] = ls2; }
    __syncthreads();
    const float Sv  = r1[0] + r1[1] + r1[2] + r1[3];
    const float Sv2 = r2[0] + r2[1] + r2[2] + r2[3];
    const float inv = 1.0f / (float)(CH * KS);
    const float m   = Sv * inv;
    const float var = Sv2 * inv - m * m;            // biased, matches ref
    const float rs  = rsqrtf(var + 1e-5f);
    float sg[KS];
    #pragma unroll
    for (int j = 0; j < KS; ++j) {
        const float vn = (v[j] - m) * rs * lng[c * KS + j] + lnb[c * KS + j];
        sg[j] = 1.0f / (1.0f + expf(-vn));
    }
    float* ko = ker + ((size_t)b * CH + c) * KK;
    #pragma unroll
    for (int i = 0; i < KK; ++i) {
        float a = 0.f;
        #pragma unroll
        for (int j = 0; j < KS; ++j) a += sg[j] * s_w1[i * KS + j];   // @ w1^T
        ko[i] = a;
    }
}

// ------- Kernel 3: depthwise 7x7 'SAME' conv, per-wave-independent tiles -------
// Block = 1 image, 4 waves = 4 row-strips of 14 output rows. Each wave stages its
// own 20x62 zero-padded tile (lane=col, b32 writes), waits lgkmcnt (wave-local,
// NO __syncthreads), then rolling-row compute: 7 b32 reads/row (consecutive-lane
// -> conflict-free) + up to 49 FMAs/row with taps in SGPRs.
__global__ __launch_bounds__(256, 6) void conv_kernel(const float* __restrict__ x,
                                                      const float* __restrict__ ker,
                                                      float* __restrict__ out) {
    __shared__ float tile[4 * TSIZE];                 // 19840 B
    const int t = threadIdx.x;
    const int wid = t >> 6, lane = t & 63;
    const int img = blockIdx.x;
    const int r0 = wid * 14;
    float* tl = tile + wid * TSIZE;
    // taps -> SGPRs (uniform address; readfirstlane pins to scalar regs)
    const float* kp = ker + (size_t)img * KK;
    float tap[KK];
    #pragma unroll
    for (int i = 0; i < KK; ++i)
        tap[i] = __int_as_float(__builtin_amdgcn_readfirstlane(__float_as_int(kp[i])));
    // stage zero-padded tile: lane c -> padded col c+3; lanes 56..61 -> pad cols
    const float* xi = x + (size_t)img * HW;
    #pragma unroll
    for (int rr = 0; rr < TROWS; ++rr) {
        const int g = r0 + rr - 3;
        if (lane < 56) {
            float v = 0.f;
            if ((unsigned)g < 56u) v = xi[g * WW + lane];
            tl[rr * TPITCH + lane + 3] = v;
        } else {
            const int j = lane - 56;
            if (j < 6) tl[rr * TPITCH + ((j < 3) ? j : 56 + j)] = 0.f;
        }
    }
    asm volatile("s_waitcnt lgkmcnt(0)" ::: "memory");
    __builtin_amdgcn_wave_barrier();
    const int cc = (lane < 56) ? lane : 55;           // clamp idle lanes in-bounds
    float acc[14];
    #pragma unroll
    for (int o = 0; o < 14; ++o) acc[o] = 0.f;
    #pragma unroll
    for (int rr = 0; rr < TROWS; ++rr) {
        float w[KS];
        #pragma unroll
        for (int kw = 0; kw < KS; ++kw) w[kw] = tl[rr * TPITCH + cc + kw];
        #pragma unroll
        for (int kr = 0; kr < KS; ++kr) {
            const int o = rr - kr;
            if (o < 0 || o > 13) continue;            // folds at compile time
            #pragma unroll
            for (int kw = 0; kw < KS; ++kw)
                acc[o] += w[kw] * tap[kr * KS + kw];
        }
    }
    if (lane < 56) {
        float* oi = out + (size_t)img * HW;
        #pragma unroll
        for (int o = 0; o < 14; ++o)
            oi[(r0 + o) * WW + lane] = acc[o];
    }
}

extern "C" void kernel_launch(void* const* d_in, const int* in_sizes, int n_in,
                              void* d_out, int out_size, void* d_ws, size_t ws_size,
                              hipStream_t stream) {
    const float* x   = (const float*)d_in[0];
    const float* bng = (const float*)d_in[1];
    const float* bnb = (const float*)d_in[2];
    const float* w0  = (const float*)d_in[3];
    const float* lng = (const float*)d_in[4];
    const float* lnb = (const float*)d_in[5];
    const float* w1  = (const float*)d_in[6];
    float* out = (float*)d_out;

    float* ws   = (float*)d_ws;
    float* p    = ws;                        // NIMG*KK floats
    float* kern = p + (size_t)NIMG * KK;     // NIMG*KK floats
    // per-image (sum,sumsq) partials in d_out scratch; conv overwrites all of out
    float2* ss  = (float2*)d_out;            // NIMG float2 = 64 KB

    hipLaunchKernelGGL(pool_kernel, dim3(NIMG / 4), dim3(256), 0, stream, x, p, ss);
    hipLaunchKernelGGL(mid_kernel,  dim3(BATCH),    dim3(256), 0, stream, p, ss,
                       bng, bnb, w0, lng, lnb, w1, kern);
    hipLaunchKernelGGL(conv_kernel, dim3(NIMG),     dim3(256), 0, stream, x, kern, out);
}

// Round 6
// 256.096 us; speedup vs baseline: 1.0232x; 1.0232x over previous
//
#include <hip/hip_runtime.h>
#include <math.h>

#define BATCH 32
#define CH    256
#define HH    56
#define WW    56
#define HW    3136
#define KS    7
#define KK    49
#define NIMG  8192           // BATCH*CH
// conv per-wave tile: 14 output rows -> 20 padded input rows x 62 padded cols
#define TPITCH 62
#define TROWS  20
#define TSIZE  (TPITCH * TROWS)   // 1240 floats per wave

// ---- Kernel 1: 8x8 block-mean pool -> p[cell][img] + per-image (sum,sumsq) ----
// 1 wave per image, no LDS, no atomics, no barriers. Lane l<56 = (r0=l/14, q=l%14):
// reads float4 at index l+56*i (dense across lanes -> 896B coalesced per instr),
// accumulates 7 cell-row partials in regs (i>>1 compile-time), then 3-step
// shuffle tree (+28,+14,+1) -> 49 cells live on 7 lanes; store + stats reduce.
__global__ __launch_bounds__(256) void pool_kernel(const float* __restrict__ x,
                                                   float* __restrict__ p,
                                                   float2* __restrict__ ss) {
    const int t = threadIdx.x, wid = t >> 6, lane = t & 63;
    const int img = blockIdx.x * 4 + wid;
    const float4* xp = (const float4*)(x + (size_t)img * HW);   // 784 float4
    float s[7] = {0.f, 0.f, 0.f, 0.f, 0.f, 0.f, 0.f};
    if (lane < 56) {
        #pragma unroll
        for (int i = 0; i < 14; ++i) {                 // row r0+4i, quad q
            const float4 v = xp[i * 56 + lane];        // lane-dense, coalesced
            s[i >> 1] += (v.x + v.y) + (v.z + v.w);    // cell-row = i>>1 (static)
        }
    }
    #pragma unroll
    for (int c = 0; c < 7; ++c) {
        s[c] += __shfl(s[c], lane + 28, 64);           // r0 {0,1}+{2,3}
        s[c] += __shfl(s[c], lane + 14, 64);           // full 8-row sum
        s[c] += __shfl(s[c], lane + 1,  64);           // quad pair -> 8x8 cell
        s[c] *= (1.0f / 64.0f);
    }
    const bool owner = (lane < 14) && !(lane & 1);     // 7 lanes own col cq=lane>>1
    const int cq = lane >> 1;
    float v = 0.f, v2 = 0.f;
    #pragma unroll
    for (int c = 0; c < 7; ++c) {
        if (owner) p[((size_t)(c * KS + cq)) * NIMG + img] = s[c];  // transposed
        v += s[c]; v2 += s[c] * s[c];
    }
    if (!owner) { v = 0.f; v2 = 0.f; }
    #pragma unroll
    for (int o = 32; o >= 1; o >>= 1) {
        v  += __shfl_down(v,  o, 64);
        v2 += __shfl_down(v2, o, 64);
    }
    if (lane == 0) ss[img] = make_float2(v, v2);
}

// --- Kernel 2: BN finalize+apply + Linear(49->7) + LN(C,7) + sigmoid + Linear(7->49) ---
__global__ __launch_bounds__(256) void mid_kernel(const float* __restrict__ p,
                                                  const float2* __restrict__ ss,
                                                  const float* __restrict__ bng,
                                                  const float* __restrict__ bnb,
                                                  const float* __restrict__ w0,
                                                  const float* __restrict__ lng,
                                                  const float* __restrict__ lnb,
                                                  const float* __restrict__ w1,
                                                  float* __restrict__ ker) {
    const int b = blockIdx.x, c = threadIdx.x;
    __shared__ float s_w0[KS * KK], s_w1[KK * KS];
    __shared__ float r1[4], r2[4];
    for (int i = c; i < KS * KK; i += 256) { s_w0[i] = w0[i]; s_w1[i] = w1[i]; }
    float S = 0.f, S2 = 0.f;
    #pragma unroll 4
    for (int bb = 0; bb < BATCH; ++bb) {
        const float2 t2 = ss[(size_t)bb * CH + c];
        S += t2.x; S2 += t2.y;
    }
    {
        const float inv  = 1.0f / (float)(BATCH * KK);
        const float mu   = S * inv;
        const float var  = S2 * inv - mu * mu;      // biased, matches ref
        const float rstd = rsqrtf(var + 1e-5f);
        S  = bng[c] * rstd;                         // scale
        S2 = bnb[c] - mu * S;                       // shift
    }
    __syncthreads();
    float pn[KK];
    const size_t base = (size_t)b * CH + c;
    #pragma unroll
    for (int i = 0; i < KK; ++i)
        pn[i] = p[(size_t)i * NIMG + base] * S + S2;   // transposed: lane-coalesced
    float v[KS];
    float ls = 0.f, ls2 = 0.f;
    #pragma unroll
    for (int j = 0; j < KS; ++j) {
        float a = 0.f;
        #pragma unroll
        for (int i = 0; i < KK; ++i) a += pn[i] * s_w0[j * KK + i];   // v = pn @ w0^T
        v[j] = a; ls += a; ls2 += a * a;
    }
    #pragma unroll
    for (int o = 32; o >= 1; o >>= 1) {
        ls  += __shfl_down(ls, o, 64);
        ls2 += __shfl_down(ls2, o, 64);
    }
    const int w = threadIdx.x >> 6;
    if ((threadIdx.x & 63) == 0) { r1[w] = ls; r2[w] = ls2; }
    __syncthreads();
    const float Sv  = r1[0] + r1[1] + r1[2] + r1[3];
    const float Sv2 = r2[0] + r2[1] + r2[2] + r2[3];
    const float inv = 1.0f / (float)(CH * KS);
    const float m   = Sv * inv;
    const float var = Sv2 * inv - m * m;            // biased, matches ref
    const float rs  = rsqrtf(var + 1e-5f);
    float sg[KS];
    #pragma unroll
    for (int j = 0; j < KS; ++j) {
        const float vn = (v[j] - m) * rs * lng[c * KS + j] + lnb[c * KS + j];
        sg[j] = 1.0f / (1.0f + expf(-vn));
    }
    float* ko = ker + base * KK;
    #pragma unroll
    for (int i = 0; i < KK; ++i) {
        float a = 0.f;
        #pragma unroll
        for (int j = 0; j < KS; ++j) a += sg[j] * s_w1[i * KS + j];   // @ w1^T
        ko[i] = a;
    }
}

// ------- Kernel 3: depthwise 7x7 'SAME' conv, per-wave-independent tiles -------
// Same structure as round 4 (dense b32 LDS, 0 measured conflicts) but with
// launch_bounds(256,4) (VGPR cap 128, was 36!) and an explicit 2-row
// double-buffered window so next-row LDS reads overlap current-row FMAs.
__global__ __launch_bounds__(256, 4) void conv_kernel(const float* __restrict__ x,
                                                      const float* __restrict__ ker,
                                                      float* __restrict__ out) {
    __shared__ float tile[4 * TSIZE];                 // 19840 B
    const int t = threadIdx.x;
    const int wid = t >> 6, lane = t & 63;
    const int img = blockIdx.x;
    const int r0 = wid * 14;
    float* tl = tile + wid * TSIZE;
    // taps -> SGPRs (uniform address; readfirstlane pins to scalar regs)
    const float* kp = ker + (size_t)img * KK;
    float tap[KK];
    #pragma unroll
    for (int i = 0; i < KK; ++i)
        tap[i] = __int_as_float(__builtin_amdgcn_readfirstlane(__float_as_int(kp[i])));
    // stage zero-padded tile: lane c -> padded col c+3; lanes 56..61 -> pad cols
    const float* xi = x + (size_t)img * HW;
    #pragma unroll
    for (int rr = 0; rr < TROWS; ++rr) {
        const int g = r0 + rr - 3;
        if (lane < 56) {
            float v = 0.f;
            if ((unsigned)g < 56u) v = xi[g * WW + lane];
            tl[rr * TPITCH + lane + 3] = v;
        } else {
            const int j = lane - 56;
            if (j < 6) tl[rr * TPITCH + ((j < 3) ? j : 56 + j)] = 0.f;
        }
    }
    asm volatile("s_waitcnt lgkmcnt(0)" ::: "memory");
    __builtin_amdgcn_wave_barrier();
    const int cc = (lane < 56) ? lane : 55;           // clamp idle lanes in-bounds
    float acc[14];
    #pragma unroll
    for (int o = 0; o < 14; ++o) acc[o] = 0.f;

    float wA[KS], wB[KS];
    #define LDROW(RR, W)                                        \
        {   const int _b = (RR) * TPITCH + cc;                  \
            _Pragma("unroll")                                   \
            for (int kw = 0; kw < KS; ++kw) W[kw] = tl[_b + kw]; }
    #define FMAROW(RR, W)                                       \
        {   _Pragma("unroll")                                   \
            for (int kr = 0; kr < KS; ++kr) {                   \
                const int o = (RR) - kr;                        \
                if (o >= 0 && o <= 13) {                        \
                    _Pragma("unroll")                           \
                    for (int kw = 0; kw < KS; ++kw)             \
                        acc[o] += W[kw] * tap[kr * KS + kw];    \
                } } }
    LDROW(0, wA);
    #pragma unroll
    for (int rr = 0; rr < TROWS; rr += 2) {
        if (rr + 1 < TROWS) LDROW(rr + 1, wB);
        FMAROW(rr, wA);
        if (rr + 2 < TROWS) LDROW(rr + 2, wA);
        if (rr + 1 < TROWS) FMAROW(rr + 1, wB);
    }
    #undef LDROW
    #undef FMAROW
    if (lane < 56) {
        float* oi = out + (size_t)img * HW;
        #pragma unroll
        for (int o = 0; o < 14; ++o)
            oi[(r0 + o) * WW + lane] = acc[o];
    }
}

extern "C" void kernel_launch(void* const* d_in, const int* in_sizes, int n_in,
                              void* d_out, int out_size, void* d_ws, size_t ws_size,
                              hipStream_t stream) {
    const float* x   = (const float*)d_in[0];
    const float* bng = (const float*)d_in[1];
    const float* bnb = (const float*)d_in[2];
    const float* w0  = (const float*)d_in[3];
    const float* lng = (const float*)d_in[4];
    const float* lnb = (const float*)d_in[5];
    const float* w1  = (const float*)d_in[6];
    float* out = (float*)d_out;

    float* ws   = (float*)d_ws;
    float* p    = ws;                        // NIMG*KK floats (layout [cell][img])
    float* kern = p + (size_t)NIMG * KK;     // NIMG*KK floats (layout [img][cell])
    // per-image (sum,sumsq) partials in d_out scratch; conv overwrites all of out
    float2* ss  = (float2*)d_out;            // NIMG float2 = 64 KB

    hipLaunchKernelGGL(pool_kernel, dim3(NIMG / 4), dim3(256), 0, stream, x, p, ss);
    hipLaunchKernelGGL(mid_kernel,  dim3(BATCH),    dim3(256), 0, stream, p, ss,
                       bng, bnb, w0, lng, lnb, w1, kern);
    hipLaunchKernelGGL(conv_kernel, dim3(NIMG),     dim3(256), 0, stream, x, kern, out);
}

// Round 8
// 252.348 us; speedup vs baseline: 1.0384x; 1.0149x over previous
//
#include <hip/hip_runtime.h>
#include <math.h>

#define BATCH 32
#define CH    256
#define HH    56
#define WW    56
#define HW    3136
#define KS    7
#define KK    49
#define NIMG  8192           // BATCH*CH
// conv per-wave tile: 14 output rows -> 20 padded input rows x 62 padded cols
#define TPITCH 62
#define TROWS  20
#define TSIZE  (TPITCH * TROWS)   // 1240 floats per wave

// ---- Kernel 1: 8x8 block-mean pool -> p[cell][img] + per-image (sum,sumsq) ----
// (round-6 verified) 1 wave/image, no LDS/atomics/barriers. Lane l<56 =
// (r0=l/14, q=l%14): 14 dense float4 loads, 7 reg partials, 3-step shuffle
// tree -> 49 cells on 7 lanes; transposed store + stats reduce.
__global__ __launch_bounds__(256) void pool_kernel(const float* __restrict__ x,
                                                   float* __restrict__ p,
                                                   float2* __restrict__ ss) {
    const int t = threadIdx.x, wid = t >> 6, lane = t & 63;
    const int img = blockIdx.x * 4 + wid;
    const float4* xp = (const float4*)(x + (size_t)img * HW);   // 784 float4
    float s[7] = {0.f, 0.f, 0.f, 0.f, 0.f, 0.f, 0.f};
    if (lane < 56) {
        #pragma unroll
        for (int i = 0; i < 14; ++i) {                 // row r0+4i, quad q
            const float4 v = xp[i * 56 + lane];        // lane-dense, coalesced
            s[i >> 1] += (v.x + v.y) + (v.z + v.w);    // cell-row = i>>1 (static)
        }
    }
    #pragma unroll
    for (int c = 0; c < 7; ++c) {
        s[c] += __shfl(s[c], lane + 28, 64);           // r0 {0,1}+{2,3}
        s[c] += __shfl(s[c], lane + 14, 64);           // full 8-row sum
        s[c] += __shfl(s[c], lane + 1,  64);           // quad pair -> 8x8 cell
        s[c] *= (1.0f / 64.0f);
    }
    const bool owner = (lane < 14) && !(lane & 1);     // 7 lanes own col cq=lane>>1
    const int cq = lane >> 1;
    float v = 0.f, v2 = 0.f;
    #pragma unroll
    for (int c = 0; c < 7; ++c) {
        if (owner) p[((size_t)(c * KS + cq)) * NIMG + img] = s[c];  // transposed
        v += s[c]; v2 += s[c] * s[c];
    }
    if (!owner) { v = 0.f; v2 = 0.f; }
    #pragma unroll
    for (int o = 32; o >= 1; o >>= 1) {
        v  += __shfl_down(v,  o, 64);
        v2 += __shfl_down(v2, o, 64);
    }
    if (lane == 0) ss[img] = make_float2(v, v2);
}

// --- Kernel 2: BN finalize+apply + Linear(49->7) + LN(C,7) + sigmoid + Linear(7->49) ---
// (round-6 verified)
__global__ __launch_bounds__(256) void mid_kernel(const float* __restrict__ p,
                                                  const float2* __restrict__ ss,
                                                  const float* __restrict__ bng,
                                                  const float* __restrict__ bnb,
                                                  const float* __restrict__ w0,
                                                  const float* __restrict__ lng,
                                                  const float* __restrict__ lnb,
                                                  const float* __restrict__ w1,
                                                  float* __restrict__ ker) {
    const int b = blockIdx.x, c = threadIdx.x;
    __shared__ float s_w0[KS * KK], s_w1[KK * KS];
    __shared__ float r1[4], r2[4];
    for (int i = c; i < KS * KK; i += 256) { s_w0[i] = w0[i]; s_w1[i] = w1[i]; }
    float S = 0.f, S2 = 0.f;
    #pragma unroll 4
    for (int bb = 0; bb < BATCH; ++bb) {
        const float2 t2 = ss[(size_t)bb * CH + c];
        S += t2.x; S2 += t2.y;
    }
    {
        const float inv  = 1.0f / (float)(BATCH * KK);
        const float mu   = S * inv;
        const float var  = S2 * inv - mu * mu;      // biased, matches ref
        const float rstd = rsqrtf(var + 1e-5f);
        S  = bng[c] * rstd;                         // scale
        S2 = bnb[c] - mu * S;                       // shift
    }
    __syncthreads();
    float pn[KK];
    const size_t base = (size_t)b * CH + c;
    #pragma unroll
    for (int i = 0; i < KK; ++i)
        pn[i] = p[(size_t)i * NIMG + base] * S + S2;   // transposed: lane-coalesced
    float v[KS];
    float ls = 0.f, ls2 = 0.f;
    #pragma unroll
    for (int j = 0; j < KS; ++j) {
        float a = 0.f;
        #pragma unroll
        for (int i = 0; i < KK; ++i) a += pn[i] * s_w0[j * KK + i];   // v = pn @ w0^T
        v[j] = a; ls += a; ls2 += a * a;
    }
    #pragma unroll
    for (int o = 32; o >= 1; o >>= 1) {
        ls  += __shfl_down(ls, o, 64);
        ls2 += __shfl_down(ls2, o, 64);
    }
    const int w = threadIdx.x >> 6;
    if ((threadIdx.x & 63) == 0) { r1[w] = ls; r2[w] = ls2; }
    __syncthreads();
    const float Sv  = r1[0] + r1[1] + r1[2] + r1[3];
    const float Sv2 = r2[0] + r2[1] + r2[2] + r2[3];
    const float inv = 1.0f / (float)(CH * KS);
    const float m   = Sv * inv;
    const float var = Sv2 * inv - m * m;            // biased, matches ref
    const float rs  = rsqrtf(var + 1e-5f);
    float sg[KS];
    #pragma unroll
    for (int j = 0; j < KS; ++j) {
        const float vn = (v[j] - m) * rs * lng[c * KS + j] + lnb[c * KS + j];
        sg[j] = 1.0f / (1.0f + expf(-vn));
    }
    float* ko = ker + base * KK;
    #pragma unroll
    for (int i = 0; i < KK; ++i) {
        float a = 0.f;
        #pragma unroll
        for (int j = 0; j < KS; ++j) a += sg[j] * s_w1[i * KS + j];   // @ w1^T
        ko[i] = a;
    }
}

// ------- Kernel 3: depthwise 7x7 'SAME' conv, ONE WAVE PER BLOCK --------------
// Body identical to round-6 (dense b32 LDS, 0 conflicts, taps in SGPR, rolling
// 2-row window) but scheduling quantum = 1 wave: 64-thr blocks, 4960B LDS each
// -> exactly 32 blocks/CU fit LDS (32*5KB=160KB) = 32 waves/CU occupancy cap
// (r6's 4-wave/20KB blocks averaged 63%). Grid 4*NIMG; bid>>2 = img keeps
// neighboring strips on one image for L2 locality.
__global__ __launch_bounds__(64) void conv_kernel(const float* __restrict__ x,
                                                  const float* __restrict__ ker,
                                                  float* __restrict__ out) {
    __shared__ float tl[TSIZE];                       // 4960 B (per-wave tile)
    const int lane = threadIdx.x;
    const int img = blockIdx.x >> 2;
    const int r0 = (blockIdx.x & 3) * 14;
    // taps -> SGPRs (uniform address; readfirstlane pins to scalar regs)
    const float* kp = ker + (size_t)img * KK;
    float tap[KK];
    #pragma unroll
    for (int i = 0; i < KK; ++i)
        tap[i] = __int_as_float(__builtin_amdgcn_readfirstlane(__float_as_int(kp[i])));
    // stage zero-padded tile: lane c -> padded col c+3; lanes 56..61 -> pad cols
    const float* xi = x + (size_t)img * HW;
    #pragma unroll
    for (int rr = 0; rr < TROWS; ++rr) {
        const int g = r0 + rr - 3;
        if (lane < 56) {
            float v = 0.f;
            if ((unsigned)g < 56u) v = xi[g * WW + lane];
            tl[rr * TPITCH + lane + 3] = v;
        } else {
            const int j = lane - 56;
            if (j < 6) tl[rr * TPITCH + ((j < 3) ? j : 56 + j)] = 0.f;
        }
    }
    asm volatile("s_waitcnt lgkmcnt(0)" ::: "memory");
    __builtin_amdgcn_wave_barrier();
    const int cc = (lane < 56) ? lane : 55;           // clamp idle lanes in-bounds
    float acc[14];
    #pragma unroll
    for (int o = 0; o < 14; ++o) acc[o] = 0.f;

    float wA[KS], wB[KS];
    #define LDROW(RR, W)                                        \
        {   const int _b = (RR) * TPITCH + cc;                  \
            _Pragma("unroll")                                   \
            for (int kw = 0; kw < KS; ++kw) W[kw] = tl[_b + kw]; }
    #define FMAROW(RR, W)                                       \
        {   _Pragma("unroll")                                   \
            for (int kr = 0; kr < KS; ++kr) {                   \
                const int o = (RR) - kr;                        \
                if (o >= 0 && o <= 13) {                        \
                    _Pragma("unroll")                           \
                    for (int kw = 0; kw < KS; ++kw)             \
                        acc[o] += W[kw] * tap[kr * KS + kw];    \
                } } }
    LDROW(0, wA);
    #pragma unroll
    for (int rr = 0; rr < TROWS; rr += 2) {
        if (rr + 1 < TROWS) LDROW(rr + 1, wB);
        FMAROW(rr, wA);
        if (rr + 2 < TROWS) LDROW(rr + 2, wA);
        if (rr + 1 < TROWS) FMAROW(rr + 1, wB);
    }
    #undef LDROW
    #undef FMAROW
    if (lane < 56) {
        float* oi = out + (size_t)img * HW;
        #pragma unroll
        for (int o = 0; o < 14; ++o)
            oi[(r0 + o) * WW + lane] = acc[o];
    }
}

extern "C" void kernel_launch(void* const* d_in, const int* in_sizes, int n_in,
                              void* d_out, int out_size, void* d_ws, size_t ws_size,
                              hipStream_t stream) {
    const float* x   = (const float*)d_in[0];
    const float* bng = (const float*)d_in[1];
    const float* bnb = (const float*)d_in[2];
    const float* w0  = (const float*)d_in[3];
    const float* lng = (const float*)d_in[4];
    const float* lnb = (const float*)d_in[5];
    const float* w1  = (const float*)d_in[6];
    float* out = (float*)d_out;

    float* ws   = (float*)d_ws;
    float* p    = ws;                        // NIMG*KK floats (layout [cell][img])
    float* kern = p + (size_t)NIMG * KK;     // NIMG*KK floats (layout [img][cell])
    // per-image (sum,sumsq) partials in d_out scratch; conv overwrites all of out
    float2* ss  = (float2*)d_out;            // NIMG float2 = 64 KB

    hipLaunchKernelGGL(pool_kernel, dim3(NIMG / 4), dim3(256), 0, stream, x, p, ss);
    hipLaunchKernelGGL(mid_kernel,  dim3(BATCH),    dim3(256), 0, stream, p, ss,
                       bng, bnb, w0, lng, lnb, w1, kern);
    hipLaunchKernelGGL(conv_kernel, dim3(NIMG * 4), dim3(64),  0, stream, x, kern, out);
}